// Round 5
// baseline (44.682 us; speedup 1.0000x reference)
//
#include <hip/hip_runtime.h>

// MaxRecallLoss: single fused kernel, fence-free last-block-done reduction.
// B = 2,097,152, C = 8. Cancer classes {0,1,3} -> mask 0xB.
//
// R2 lesson: per-block __threadfence() => buffer_wbl2 (L2 writeback) x 2048
// => 4x regression. Here: partials are RELAXED AGENT-scope atomic stores
// (sc1 -> coherent point, never dirty in L2), ordered before the completion
// counter by a wave-local s_waitcnt vmcnt(0). No wbl2, no inv, no spin.
//
// d_ws layout (floats): [0,NB) ce | [NB,2NB) tp | [2NB,3NB) cnt | counter.

constexpr int C   = 8;
constexpr int NT  = 256;   // threads per block
constexpr int NB  = 2048;  // NB*NT*RPT == 2^21 == B exactly
constexpr int RPT = 4;     // rows per thread

__device__ __forceinline__ float wave_reduce_sum(float v) {
    #pragma unroll
    for (int off = 32; off > 0; off >>= 1) v += __shfl_down(v, off, 64);
    return v;
}

__device__ __forceinline__ void row_loss(const float l[8], int t,
                                         const float* s_bw,
                                         float& ce_sum, float& tp_sum,
                                         float& cnt_sum) {
    const float inv_temp = 1.0f / 1.5f;
    const float c_uni   = 0.05f / 8.0f;
    const float c_one   = 1.0f - 0.05f;
    const float b_uni   = 0.1f / 8.0f;
    const float b_one   = 1.0f - 0.1f;
    const float b_extra = 0.1f * 0.5f / 3.0f;
    const float b_norm  = 1.0f / (1.0f + 3.0f * (0.1f * 0.5f / 3.0f)); // 1/1.05

    // max + argmax (first-max tie-break, matches jnp.argmax)
    float m = l[0];
    int   p = 0;
    #pragma unroll
    for (int j = 1; j < 8; ++j) { if (l[j] > m) { m = l[j]; p = j; } }

    // temp-1 softmax pieces (cancer prob)
    float se = 0.0f, e0, e1, e3;
    {
        float e[8];
        #pragma unroll
        for (int j = 0; j < 8; ++j) { e[j] = __expf(l[j] - m); se += e[j]; }
        e0 = e[0]; e1 = e[1]; e3 = e[3];
    }
    const float cp = (e0 + e1 + e3) / se;

    // temp-1.5 log-sum-exp
    float se2 = 0.0f;
    #pragma unroll
    for (int j = 0; j < 8; ++j) se2 += __expf((l[j] - m) * inv_temp);
    const float logZ = m * inv_temp + __logf(se2);

    // dot(smoothed_labels, x) without materializing the row
    float S = 0.0f;
    #pragma unroll
    for (int j = 0; j < 8; ++j) S += l[j];
    const float X  = S * inv_temp;
    const float Xc = (l[0] + l[1] + l[3]) * inv_temp;
    float lt = l[0];
    #pragma unroll
    for (int j = 1; j < 8; ++j) lt = (t == j) ? l[j] : lt;
    const float xt = lt * inv_temp;

    const bool isct = ((1u << t) & 0xBu) != 0u;
    const bool iscp = ((1u << p) & 0xBu) != 0u;

    float dot;
    if (isct) dot = c_uni * X + c_one * xt;
    else      dot = (b_uni * X + b_one * xt + b_extra * Xc) * b_norm;

    float ce = (logZ - dot) * s_bw[t];

    float mult = (isct && !iscp) ? 3.0f : 1.0f;
    if (t == 0 && !iscp) mult = 5.0f;
    if (isct && p != t) mult *= 2.0f;
    ce *= mult;

    ce_sum += ce;
    if (isct) { tp_sum += cp; cnt_sum += 1.0f; }
}

__global__ __launch_bounds__(NT) void mrl_fused(
    const float* __restrict__ logits,
    const int*   __restrict__ targets,
    const float* __restrict__ counts,
    float*        part,     // [3*NB] coherent partials
    unsigned int* counter,  // zeroed via memset node each call
    float*        out,
    int B)
{
    __shared__ float s_bw[C];
    __shared__ float s_red[(NT / 64) * 3];
    __shared__ int   s_last;

    if (threadIdx.x == 0) {
        float w[C];
        float ws = 0.0f;
        #pragma unroll
        for (int c = 0; c < C; ++c) { w[c] = rsqrtf(counts[c] + 1.0f); ws += w[c]; }
        const float scale = (float)C / ws;
        #pragma unroll
        for (int c = 0; c < C; ++c) s_bw[c] = w[c] * scale;
    }
    __syncthreads();

    float ce_sum = 0.0f, tp_sum = 0.0f, cnt_sum = 0.0f;

    const long tid  = (long)blockIdx.x * NT + threadIdx.x;
    const long base = tid * RPT;

    if (base + RPT <= B) {
        // fast path (always for B = 2^21): issue ALL loads up front
        const float4* rowp = reinterpret_cast<const float4*>(logits + base * 8);
        float4 r[2 * RPT];
        #pragma unroll
        for (int q = 0; q < 2 * RPT; ++q) r[q] = rowp[q];
        const int4 t4 = *reinterpret_cast<const int4*>(targets + base);
        const int ts[RPT] = {t4.x, t4.y, t4.z, t4.w};

        #pragma unroll
        for (int j = 0; j < RPT; ++j) {
            const float l[8] = {r[2*j].x,   r[2*j].y,   r[2*j].z,   r[2*j].w,
                                r[2*j+1].x, r[2*j+1].y, r[2*j+1].z, r[2*j+1].w};
            row_loss(l, ts[j], s_bw, ce_sum, tp_sum, cnt_sum);
        }
    } else {
        for (long i = base; i < B; ++i) {
            const float4* row = reinterpret_cast<const float4*>(logits + i * 8);
            const float4 a = row[0];
            const float4 b = row[1];
            const float l[8] = {a.x, a.y, a.z, a.w, b.x, b.y, b.z, b.w};
            row_loss(l, targets[i], s_bw, ce_sum, tp_sum, cnt_sum);
        }
    }

    // block reduction (fixed order -> deterministic)
    float v0 = wave_reduce_sum(ce_sum);
    float v1 = wave_reduce_sum(tp_sum);
    float v2 = wave_reduce_sum(cnt_sum);
    const int lane = threadIdx.x & 63;
    const int wid  = threadIdx.x >> 6;
    if (lane == 0) {
        s_red[wid * 3 + 0] = v0;
        s_red[wid * 3 + 1] = v1;
        s_red[wid * 3 + 2] = v2;
    }
    __syncthreads();
    if (threadIdx.x == 0) {
        float r0 = 0.0f, r1 = 0.0f, r2 = 0.0f;
        #pragma unroll
        for (int w = 0; w < NT / 64; ++w) {
            r0 += s_red[w * 3 + 0];
            r1 += s_red[w * 3 + 1];
            r2 += s_red[w * 3 + 2];
        }
        // coherent (L2-bypassing) relaxed stores of this block's partials
        __hip_atomic_store(&part[blockIdx.x],          r0, __ATOMIC_RELAXED, __HIP_MEMORY_SCOPE_AGENT);
        __hip_atomic_store(&part[NB + blockIdx.x],     r1, __ATOMIC_RELAXED, __HIP_MEMORY_SCOPE_AGENT);
        __hip_atomic_store(&part[2 * NB + blockIdx.x], r2, __ATOMIC_RELAXED, __HIP_MEMORY_SCOPE_AGENT);
        // order the partial stores before the completion increment
        // (wave-local wait for write-acks; NOT a cache-flushing fence)
        asm volatile("s_waitcnt vmcnt(0)" ::: "memory");
        const unsigned prev =
            __hip_atomic_fetch_add(counter, 1u, __ATOMIC_RELAXED, __HIP_MEMORY_SCOPE_AGENT);
        s_last = (prev == (unsigned)(NB - 1)) ? 1 : 0;
    }
    __syncthreads();

    if (s_last) {
        float ce = 0.0f, tp = 0.0f, cnt = 0.0f;
        for (int k = threadIdx.x; k < NB; k += NT) {
            ce  += __hip_atomic_load(&part[k],          __ATOMIC_RELAXED, __HIP_MEMORY_SCOPE_AGENT);
            tp  += __hip_atomic_load(&part[NB + k],     __ATOMIC_RELAXED, __HIP_MEMORY_SCOPE_AGENT);
            cnt += __hip_atomic_load(&part[2 * NB + k], __ATOMIC_RELAXED, __HIP_MEMORY_SCOPE_AGENT);
        }
        float w0 = wave_reduce_sum(ce);
        float w1 = wave_reduce_sum(tp);
        float w2 = wave_reduce_sum(cnt);
        if (lane == 0) {
            s_red[wid * 3 + 0] = w0;
            s_red[wid * 3 + 1] = w1;
            s_red[wid * 3 + 2] = w2;
        }
        __syncthreads();
        if (threadIdx.x == 0) {
            float r0 = 0.0f, r1 = 0.0f, r2 = 0.0f;
            #pragma unroll
            for (int w = 0; w < NT / 64; ++w) {
                r0 += s_red[w * 3 + 0];
                r1 += s_red[w * 3 + 1];
                r2 += s_red[w * 3 + 2];
            }
            const float base_loss   = r0 / (float)B;
            const float recall_loss = 1.0f - r1 / (r2 + 1e-8f);
            out[0] = base_loss + 0.5f * recall_loss;
        }
    }
}

extern "C" void kernel_launch(void* const* d_in, const int* in_sizes, int n_in,
                              void* d_out, int out_size, void* d_ws, size_t ws_size,
                              hipStream_t stream) {
    const float* logits  = (const float*)d_in[0];
    const int*   targets = (const int*)d_in[1];
    const float* counts  = (const float*)d_in[2];
    float* out  = (float*)d_out;
    float* part = (float*)d_ws;                          // 3*NB floats
    unsigned int* counter = (unsigned int*)(part + 3 * NB);

    const int B = in_sizes[1];

    hipMemsetAsync(counter, 0, sizeof(unsigned int), stream);
    mrl_fused<<<NB, NT, 0, stream>>>(logits, targets, counts, part, counter, out, B);
}

// Round 6
// 23.716 us; speedup vs baseline: 1.8841x; 1.8841x over previous
//
#include <hip/hip_runtime.h>

// MaxRecallLoss: pass1 = barrier-free-prologue streamer (4 rows/thread,
// exact cover of B = 2^21), pass2 = single-wave LDS-free final reduce.
// Cancer classes {0,1,3} -> mask 0xB.
//
// R2/R5 lesson: single-counter last-block-done costs ~25 us in cross-XCD
// same-line RMW serialization (plus ~45 us more if threadfence/wbl2 is
// involved). Two kernels is the right structure on 8-XCD gfx950.

constexpr int C   = 8;
constexpr int NT  = 512;   // pass1 threads per block (8 waves)
constexpr int NB  = 1024;  // pass1 blocks: NB*NT*RPT == 2^21 == B exactly
constexpr int RPT = 4;     // rows per thread

__device__ __forceinline__ float wave_reduce_sum(float v) {
    #pragma unroll
    for (int off = 32; off > 0; off >>= 1) v += __shfl_down(v, off, 64);
    return v;
}

__device__ __forceinline__ void row_loss(const float l[8], int t, float bw,
                                         float& ce_sum, float& tp_sum,
                                         float& cnt_sum) {
    const float inv_temp = 1.0f / 1.5f;
    const float c_uni   = 0.05f / 8.0f;
    const float c_one   = 1.0f - 0.05f;
    const float b_uni   = 0.1f / 8.0f;
    const float b_one   = 1.0f - 0.1f;
    const float b_extra = 0.1f * 0.5f / 3.0f;
    const float b_norm  = 1.0f / (1.0f + 3.0f * (0.1f * 0.5f / 3.0f)); // 1/1.05

    // max + argmax (first-max tie-break, matches jnp.argmax)
    float m = l[0];
    int   p = 0;
    #pragma unroll
    for (int j = 1; j < 8; ++j) { if (l[j] > m) { m = l[j]; p = j; } }

    // temp-1 softmax pieces (cancer prob)
    float se = 0.0f, e0, e1, e3;
    {
        float e[8];
        #pragma unroll
        for (int j = 0; j < 8; ++j) { e[j] = __expf(l[j] - m); se += e[j]; }
        e0 = e[0]; e1 = e[1]; e3 = e[3];
    }
    const float cp = (e0 + e1 + e3) / se;

    // temp-1.5 log-sum-exp
    float se2 = 0.0f;
    #pragma unroll
    for (int j = 0; j < 8; ++j) se2 += __expf((l[j] - m) * inv_temp);
    const float logZ = m * inv_temp + __logf(se2);

    // dot(smoothed_labels, x) without materializing the row
    float S = 0.0f;
    #pragma unroll
    for (int j = 0; j < 8; ++j) S += l[j];
    const float X  = S * inv_temp;
    const float Xc = (l[0] + l[1] + l[3]) * inv_temp;
    float lt = l[0];
    #pragma unroll
    for (int j = 1; j < 8; ++j) lt = (t == j) ? l[j] : lt;
    const float xt = lt * inv_temp;

    const bool isct = ((1u << t) & 0xBu) != 0u;
    const bool iscp = ((1u << p) & 0xBu) != 0u;

    float dot;
    if (isct) dot = c_uni * X + c_one * xt;
    else      dot = (b_uni * X + b_one * xt + b_extra * Xc) * b_norm;

    float ce = (logZ - dot) * bw;

    float mult = (isct && !iscp) ? 3.0f : 1.0f;
    if (t == 0 && !iscp) mult = 5.0f;
    if (isct && p != t) mult *= 2.0f;
    ce *= mult;

    ce_sum += ce;
    if (isct) { tp_sum += cp; cnt_sum += 1.0f; }
}

__global__ __launch_bounds__(NT) void mrl_pass1(
    const float* __restrict__ logits,
    const int*   __restrict__ targets,
    const float* __restrict__ counts,
    float*       __restrict__ part,   // [3*NB]: ce | tp | cnt
    int B)
{
    __shared__ float s_red[(NT / 64) * 3];

    // Per-thread class weights (uniform across threads -> scalar loads,
    // no LDS, no prologue barrier). w[c] kept in registers.
    float w[C];
    float ws = 0.0f;
    #pragma unroll
    for (int c = 0; c < C; ++c) { w[c] = rsqrtf(counts[c] + 1.0f); ws += w[c]; }
    const float scale = (float)C / ws;

    float ce_sum = 0.0f, tp_sum = 0.0f, cnt_sum = 0.0f;

    const long tid  = (long)blockIdx.x * NT + threadIdx.x;
    const long base = tid * RPT;

    if (base + RPT <= B) {
        // fast path (always for B = 2^21): issue ALL loads up front
        const float4* rowp = reinterpret_cast<const float4*>(logits + base * 8);
        float4 r[2 * RPT];
        #pragma unroll
        for (int q = 0; q < 2 * RPT; ++q) r[q] = rowp[q];
        const int4 t4 = *reinterpret_cast<const int4*>(targets + base);
        const int ts[RPT] = {t4.x, t4.y, t4.z, t4.w};

        #pragma unroll
        for (int j = 0; j < RPT; ++j) {
            const int t = ts[j];
            float bw = w[0];
            #pragma unroll
            for (int c = 1; c < C; ++c) bw = (t == c) ? w[c] : bw;
            bw *= scale;
            const float l[8] = {r[2*j].x,   r[2*j].y,   r[2*j].z,   r[2*j].w,
                                r[2*j+1].x, r[2*j+1].y, r[2*j+1].z, r[2*j+1].w};
            row_loss(l, t, bw, ce_sum, tp_sum, cnt_sum);
        }
    } else {
        // generic tail (unused when B divides evenly)
        for (long i = base; i < B; ++i) {
            const float4* row = reinterpret_cast<const float4*>(logits + i * 8);
            const float4 a = row[0];
            const float4 b = row[1];
            const float l[8] = {a.x, a.y, a.z, a.w, b.x, b.y, b.z, b.w};
            const int t = targets[i];
            float bw = w[0];
            #pragma unroll
            for (int c = 1; c < C; ++c) bw = (t == c) ? w[c] : bw;
            bw *= scale;
            row_loss(l, t, bw, ce_sum, tp_sum, cnt_sum);
        }
    }

    // block reduction (fixed order -> deterministic)
    float v0 = wave_reduce_sum(ce_sum);
    float v1 = wave_reduce_sum(tp_sum);
    float v2 = wave_reduce_sum(cnt_sum);
    const int lane = threadIdx.x & 63;
    const int wid  = threadIdx.x >> 6;
    if (lane == 0) {
        s_red[wid * 3 + 0] = v0;
        s_red[wid * 3 + 1] = v1;
        s_red[wid * 3 + 2] = v2;
    }
    __syncthreads();
    if (threadIdx.x == 0) {
        float r0 = 0.0f, r1 = 0.0f, r2 = 0.0f;
        #pragma unroll
        for (int w2 = 0; w2 < NT / 64; ++w2) {
            r0 += s_red[w2 * 3 + 0];
            r1 += s_red[w2 * 3 + 1];
            r2 += s_red[w2 * 3 + 2];
        }
        part[blockIdx.x]          = r0;
        part[NB + blockIdx.x]     = r1;
        part[2 * NB + blockIdx.x] = r2;
    }
}

// Single-wave, LDS-free, barrier-free final reduce.
__global__ __launch_bounds__(64) void mrl_pass2(
    const float* __restrict__ part,
    float*       __restrict__ out,
    int B)
{
    const float4* p4 = reinterpret_cast<const float4*>(part);
    const int lane = threadIdx.x;           // 0..63
    constexpr int SEG = NB / 4;             // float4 per segment = 256

    // issue all 12 loads up front
    float4 a[4], b[4], c[4];
    #pragma unroll
    for (int q = 0; q < 4; ++q) a[q] = p4[lane + q * 64];
    #pragma unroll
    for (int q = 0; q < 4; ++q) b[q] = p4[SEG + lane + q * 64];
    #pragma unroll
    for (int q = 0; q < 4; ++q) c[q] = p4[2 * SEG + lane + q * 64];

    float ce = 0.0f, tp = 0.0f, cnt = 0.0f;
    #pragma unroll
    for (int q = 0; q < 4; ++q) {
        ce  += (a[q].x + a[q].y) + (a[q].z + a[q].w);
        tp  += (b[q].x + b[q].y) + (b[q].z + b[q].w);
        cnt += (c[q].x + c[q].y) + (c[q].z + c[q].w);
    }
    ce  = wave_reduce_sum(ce);
    tp  = wave_reduce_sum(tp);
    cnt = wave_reduce_sum(cnt);
    if (lane == 0) {
        const float base_loss   = ce / (float)B;
        const float recall_loss = 1.0f - tp / (cnt + 1e-8f);
        out[0] = base_loss + 0.5f * recall_loss;
    }
}

extern "C" void kernel_launch(void* const* d_in, const int* in_sizes, int n_in,
                              void* d_out, int out_size, void* d_ws, size_t ws_size,
                              hipStream_t stream) {
    const float* logits  = (const float*)d_in[0];
    const int*   targets = (const int*)d_in[1];
    const float* counts  = (const float*)d_in[2];
    float* out  = (float*)d_out;
    float* part = (float*)d_ws;   // 3*NB floats = 12 KB scratch
    const int B = in_sizes[1];

    mrl_pass1<<<NB, NT, 0, stream>>>(logits, targets, counts, part, B);
    mrl_pass2<<<1, 64, 0, stream>>>(part, out, B);
}